// Round 19
// baseline (18.940 us; speedup 1.0000x reference)
//
#include <hip/hip_runtime.h>

#define NEG_SLOPE 0.01f

typedef _Float16 f16;
typedef _Float16 f16x4 __attribute__((ext_vector_type(4)));
typedef float    f32x4 __attribute__((ext_vector_type(4)));

__device__ __forceinline__ float leaky(float v) {
    return fmaxf(v, NEG_SLOPE * v);
}

// ---- R18 structure + pre-built B fragments (full 3-stage software pipeline) ----
// 1024 blocks x 256 thr. Wave wv owns rows (ia, ia+1), ia = blockIdx*8 + wv*2.
// Pipeline state at entry of iter T:
//   b1aC/b1bC = B-fragments for tile T (pre-built), sgC = sig tile T
//   pjN/sgN   = raw pj + sig for tile T+1
//   dpa/dpb   = MFMA results tile T-1, spa/spb = sig tile T-1
// Iter T: prefetch raw T+2; MFMA tile T (no VALU dependency at issue);
//         build b1 tile T+1 and accumulate tile T-1 (both overlap MFMA).
__global__ __launch_bounds__(256, 4) void fused_pipe3(
    const float* __restrict__ x,
    const float* __restrict__ Wn1, const float* __restrict__ bn1,
    const float* __restrict__ Wn2, const float* __restrict__ bn2,
    const float* __restrict__ Wn3, const float* __restrict__ bn3,
    const float* __restrict__ Wc1, const float* __restrict__ bc1,
    const float* __restrict__ Wc2, const float* __restrict__ bc2,
    const float* __restrict__ Wc3, const float* __restrict__ bc3,
    const float* __restrict__ A_param,
    float* __restrict__ out)
{
    __shared__ unsigned char pjbuf[512 * 32];   // f16 [512][16], swizzled
    __shared__ float2 shn[4][64];               // node h1 pairs, per wave
    __shared__ float2 sigbuf[4][512];           // sigmoid pairs, per wave

    const int t  = threadIdx.x;
    const int l  = t & 63;
    const int wv = t >> 6;
    const int p  = l & 15;            // pair slot within 16-j tile
    const int g  = l >> 4;            // channel group
    const int c4 = g << 2;
    const int ia = blockIdx.x * 8 + wv * 2;   // even global row (b*512 + i0)
    const int ib = ia + 1;
    const int bb = ia >> 9;
    const int i0 = ia & 511, i1 = i0 + 1;

    const float* xb = x + bb * 1024;  // x[b][j][2]

    // ---- Phase 1a: stage pj (f16) into LDS; thread t covers j = t, t+256 ----
    #pragma unroll
    for (int jj = 0; jj < 2; ++jj) {
        const int j = t + jj * 256;
        const float2 xj = *reinterpret_cast<const float2*>(xb + j * 2);
        f16 v[16];
        #pragma unroll
        for (int c = 0; c < 16; ++c)
            v[c] = (f16)fmaf(xj.x, Wc1[c], xj.y * Wc1[16 + c]);
        const int sw = ((j >> 2) & 3) << 3;
        #pragma unroll
        for (int gg = 0; gg < 4; ++gg) {
            const int addr = j * 32 + ((gg << 3) ^ sw);
            *reinterpret_cast<f16x4*>(pjbuf + addr) =
                (f16x4){v[4*gg], v[4*gg+1], v[4*gg+2], v[4*gg+3]};
        }
    }

    const float2 xia = *reinterpret_cast<const float2*>(xb + i0 * 2);
    const float2 xib = *reinterpret_cast<const float2*>(xb + i1 * 2);

    // ---- Phase 1b: weight fragments (row-independent) + per-row piu ----
    f16x4 w2h, piua, piub;
    f32x4 c1;
    float w3p[4], w3a[4];
    #pragma unroll
    for (int e = 0; e < 4; ++e) {
        const int c = c4 + e;
        w2h[e] = (f16)Wc2[c * 16 + p];       // RTN f16 (single-MFMA path)
        c1[e]  = bc2[c];
        const float w3 = Wc3[c];
        w3p[e] = 0.505f * w3;
        w3a[e] = 0.495f * w3;
        const float wi0 = Wc1[32 + c], wi1 = Wc1[48 + c], bce = bc1[c];
        piua[e] = (f16)fmaf(xia.x, wi0, fmaf(xia.y, wi1, bce));
        piub[e] = (f16)fmaf(xib.x, wi0, fmaf(xib.y, wi1, bce));
    }
    const f16x4 slope4 = {(f16)NEG_SLOPE, (f16)NEG_SLOPE, (f16)NEG_SLOPE, (f16)NEG_SLOPE};

    // ---- Phase 1c: node MLP for both rows (shared Wn2 loads, split chains) ----
    const float h1a = leaky(fmaf(xia.x, Wn1[l], fmaf(xia.y, Wn1[64 + l], bn1[l])));
    const float h1b = leaky(fmaf(xib.x, Wn1[l], fmaf(xib.y, Wn1[64 + l], bn1[l])));
    shn[wv][l] = make_float2(h1a, h1b);
    float na0 = bn2[l], nb0 = 0.f, na1 = 0.f, nb1 = 0.f;
    #pragma unroll 8
    for (int c = 0; c < 64; c += 2) {
        const float w0 = Wn2[c * 64 + l];
        const float w1 = Wn2[(c + 1) * 64 + l];
        const float2 h0 = shn[wv][c];
        const float2 h2 = shn[wv][c + 1];
        na0 = fmaf(h0.x, w0, na0);
        nb0 = fmaf(h0.y, w0, nb0);
        na1 = fmaf(h2.x, w1, na1);
        nb1 = fmaf(h2.y, w1, nb1);
    }
    const float node_a = leaky(na0 + na1) * Wn3[l];
    const float node_b = leaky(nb0 + nb1 + bn2[l]) * Wn3[l];

    // ---- Phase 1d: sigmoid rows for both i's -> LDS (intra-wave use) ----
    float vsa = 0.f, vsb = 0.f;
    const float* Ara = A_param + i0 * 512;
    const float* Arb = Ara + 512;
    #pragma unroll
    for (int s = 0; s < 8; ++s) {
        const int j = s * 64 + l;
        float sa = __fdividef(1.f, 1.f + __expf(-Ara[j]));
        float sb = __fdividef(1.f, 1.f + __expf(-Arb[j]));
        if (j == i0) sa = 0.f;        // sigmoid(0 - 1e5) == 0 in f32
        if (j == i1) sb = 0.f;
        vsa += sa; vsb += sb;
        sigbuf[wv][j] = make_float2(sa, sb);
    }

    __syncthreads();   // pjbuf staging complete (shn/sigbuf are intra-wave)

    // ---- Phase 2: 32 subtiles; 3-stage pipeline ----
    const int rbase = p * 32 + ((g << 3) ^ (((p >> 2) & 3) << 3));
    float pA0=0.f,pA1=0.f,pA2=0.f,pA3=0.f, qA0=0.f,qA1=0.f,qA2=0.f,qA3=0.f;
    float pB0=0.f,pB1=0.f,pB2=0.f,pB3=0.f, qB0=0.f,qB1=0.f,qB2=0.f,qB3=0.f;

    // prologue: tile 0 -> MFMA in flight; tile 1 -> b1 pre-built; tile 2 -> raw
    f16x4 raw0 = *reinterpret_cast<const f16x4*>(pjbuf + rbase);            // tile 0
    {
        // MFMA tile 0
        const f16x4 s4a = raw0 + piua;
        const f16x4 s4b = raw0 + piub;
        const f16x4 b1a0 = __builtin_elementwise_max(s4a, s4a * slope4);
        const f16x4 b1b0 = __builtin_elementwise_max(s4b, s4b * slope4);
        raw0 = b1a0;  // reuse reg slot below via explicit vars instead
        // (explicit names used; see dpa/dpb init)
        (void)b1b0;
    }
    // redo cleanly with named state:
    f16x4 r0 = *reinterpret_cast<const f16x4*>(pjbuf + rbase);              // tile 0
    f16x4 s4a0 = r0 + piua, s4b0 = r0 + piub;
    f16x4 b1a0 = __builtin_elementwise_max(s4a0, s4a0 * slope4);
    f16x4 b1b0 = __builtin_elementwise_max(s4b0, s4b0 * slope4);
    f32x4 dpa = __builtin_amdgcn_mfma_f32_16x16x16f16(w2h, b1a0, c1, 0, 0, 0);
    f32x4 dpb = __builtin_amdgcn_mfma_f32_16x16x16f16(w2h, b1b0, c1, 0, 0, 0);
    const float2 sgt0 = sigbuf[wv][p];
    float spa = sgt0.x, spb = sgt0.y;                                       // sig tile 0

    f16x4 r1 = *reinterpret_cast<const f16x4*>(pjbuf + rbase + 512);        // tile 1
    f16x4 s4a1 = r1 + piua, s4b1 = r1 + piub;
    f16x4 b1aC = __builtin_elementwise_max(s4a1, s4a1 * slope4);
    f16x4 b1bC = __builtin_elementwise_max(s4b1, s4b1 * slope4);
    float2 sgC = sigbuf[wv][16 + p];                                        // sig tile 1

    f16x4  pjN = *reinterpret_cast<const f16x4*>(pjbuf + rbase + 2 * 512);  // tile 2
    float2 sgN = sigbuf[wv][2 * 16 + p];

    #pragma unroll 4
    for (int T = 1; T < 32; ++T) {
        // prefetch raw tile T+2 (wraps to dummy on last two iters)
        const int Tn = (T + 2) & 31;
        const f16x4  pjn2 = *reinterpret_cast<const f16x4*>(pjbuf + rbase + Tn * 512);
        const float2 sgn2 = sigbuf[wv][Tn * 16 + p];

        // issue tile T's MFMAs from PRE-BUILT fragments (no VALU dependency)
        const f32x4 dca = __builtin_amdgcn_mfma_f32_16x16x16f16(w2h, b1aC, c1, 0, 0, 0);
        const f32x4 dcb = __builtin_amdgcn_mfma_f32_16x16x16f16(w2h, b1bC, c1, 0, 0, 0);

        // build b1 for tile T+1 (overlaps MFMAs)
        const f16x4 s4a = pjN + piua;
        const f16x4 s4b = pjN + piub;
        const f16x4 b1aN = __builtin_elementwise_max(s4a, s4a * slope4);
        const f16x4 b1bN = __builtin_elementwise_max(s4b, s4b * slope4);

        // accumulate tile T-1's results (overlaps MFMAs)
        pA0 = fmaf(spa, dpa[0], pA0);  qA0 = fmaf(spa, fabsf(dpa[0]), qA0);
        pA1 = fmaf(spa, dpa[1], pA1);  qA1 = fmaf(spa, fabsf(dpa[1]), qA1);
        pA2 = fmaf(spa, dpa[2], pA2);  qA2 = fmaf(spa, fabsf(dpa[2]), qA2);
        pA3 = fmaf(spa, dpa[3], pA3);  qA3 = fmaf(spa, fabsf(dpa[3]), qA3);
        pB0 = fmaf(spb, dpb[0], pB0);  qB0 = fmaf(spb, fabsf(dpb[0]), qB0);
        pB1 = fmaf(spb, dpb[1], pB1);  qB1 = fmaf(spb, fabsf(dpb[1]), qB1);
        pB2 = fmaf(spb, dpb[2], pB2);  qB2 = fmaf(spb, fabsf(dpb[2]), qB2);
        pB3 = fmaf(spb, dpb[3], pB3);  qB3 = fmaf(spb, fabsf(dpb[3]), qB3);

        // rotate pipeline
        dpa = dca; dpb = dcb;
        spa = sgC.x; spb = sgC.y;     // sig of tile T (just MFMA'd)
        b1aC = b1aN; b1bC = b1bN; sgC = sgN;   // tile T+1 pre-built
        pjN = pjn2; sgN = sgn2;                // tile T+2 raw
    }

    // epilogue: accumulate tile 31's results
    pA0 = fmaf(spa, dpa[0], pA0);  qA0 = fmaf(spa, fabsf(dpa[0]), qA0);
    pA1 = fmaf(spa, dpa[1], pA1);  qA1 = fmaf(spa, fabsf(dpa[1]), qA1);
    pA2 = fmaf(spa, dpa[2], pA2);  qA2 = fmaf(spa, fabsf(dpa[2]), qA2);
    pA3 = fmaf(spa, dpa[3], pA3);  qA3 = fmaf(spa, fabsf(dpa[3]), qA3);
    pB0 = fmaf(spb, dpb[0], pB0);  qB0 = fmaf(spb, fabsf(dpb[0]), qB0);
    pB1 = fmaf(spb, dpb[1], pB1);  qB1 = fmaf(spb, fabsf(dpb[1]), qB1);
    pB2 = fmaf(spb, dpb[2], pB2);  qB2 = fmaf(spb, fabsf(dpb[2]), qB2);
    pB3 = fmaf(spb, dpb[3], pB3);  qB3 = fmaf(spb, fabsf(dpb[3]), qB3);

    // ---- Epilogue: leaky fold (0.505/0.495 in w3p/w3a), node, butterfly ----
    float ppa = pA0*w3p[0] + qA0*w3a[0] + pA1*w3p[1] + qA1*w3a[1]
              + pA2*w3p[2] + qA2*w3a[2] + pA3*w3p[3] + qA3*w3a[3];
    float ppb = pB0*w3p[0] + qB0*w3a[0] + pB1*w3p[1] + qB1*w3a[1]
              + pB2*w3p[2] + qB2*w3a[2] + pB3*w3p[3] + qB3*w3a[3];

    ppa = fmaf(bc3[0], vsa, ppa) + node_a;
    ppb = fmaf(bc3[0], vsb, ppb) + node_b;

    #pragma unroll
    for (int off = 32; off > 0; off >>= 1) {
        ppa += __shfl_xor(ppa, off, 64);
        ppb += __shfl_xor(ppb, off, 64);
    }

    if (l == 0) {
        out[ia * 2 + 0] = xia.y;               // out0 = x[...,1]
        out[ia * 2 + 1] = ppa + bn3[0];
        out[ib * 2 + 0] = xib.y;
        out[ib * 2 + 1] = ppb + bn3[0];
    }
}

extern "C" void kernel_launch(void* const* d_in, const int* in_sizes, int n_in,
                              void* d_out, int out_size, void* d_ws, size_t ws_size,
                              hipStream_t stream) {
    const float* x       = (const float*)d_in[0];
    const float* Wn1     = (const float*)d_in[1];
    const float* bn1     = (const float*)d_in[2];
    const float* Wn2     = (const float*)d_in[3];
    const float* bn2     = (const float*)d_in[4];
    const float* Wn3     = (const float*)d_in[5];
    const float* bn3     = (const float*)d_in[6];
    const float* Wc1     = (const float*)d_in[7];
    const float* bc1     = (const float*)d_in[8];
    const float* Wc2     = (const float*)d_in[9];
    const float* bc2     = (const float*)d_in[10];
    const float* Wc3     = (const float*)d_in[11];
    const float* bc3     = (const float*)d_in[12];
    const float* A_param = (const float*)d_in[13];
    float* out = (float*)d_out;

    const int BN = 16 * 512;          // 8192 rows; 8 per block (2 per wave)

    fused_pipe3<<<BN / 8, 256, 0, stream>>>(x, Wn1, bn1, Wn2, bn2, Wn3, bn3,
                                            Wc1, bc1, Wc2, bc2, Wc3, bc3,
                                            A_param, out);
}

// Round 20
// 18.693 us; speedup vs baseline: 1.0133x; 1.0133x over previous
//
#include <hip/hip_runtime.h>

#define NEG_SLOPE 0.01f

typedef _Float16 f16;
typedef _Float16 f16x4 __attribute__((ext_vector_type(4)));
typedef float    f32x4 __attribute__((ext_vector_type(4)));

__device__ __forceinline__ float leaky(float v) {
    return fmaxf(v, NEG_SLOPE * v);
}

// ------- Best-measured kernel (R18): single-MFMA + depth-2 LDS prefetch +
// ------- 1-stage MFMA result pipeline. 18.69 us, absmax 0.0625.
// 1024 blocks x 256 thr. Wave wv owns rows (ia, ia+1), ia = blockIdx*8 + wv*2.
// Pipeline: at entry of iter T, pj0 = tile T, pj1 = tile T+1; prefetch T+2;
// accumulate tile T-1's MFMA results while tile T's MFMAs are in flight.
__global__ __launch_bounds__(256, 4) void fused_pipe2(
    const float* __restrict__ x,
    const float* __restrict__ Wn1, const float* __restrict__ bn1,
    const float* __restrict__ Wn2, const float* __restrict__ bn2,
    const float* __restrict__ Wn3, const float* __restrict__ bn3,
    const float* __restrict__ Wc1, const float* __restrict__ bc1,
    const float* __restrict__ Wc2, const float* __restrict__ bc2,
    const float* __restrict__ Wc3, const float* __restrict__ bc3,
    const float* __restrict__ A_param,
    float* __restrict__ out)
{
    __shared__ unsigned char pjbuf[512 * 32];   // f16 [512][16], swizzled
    __shared__ float2 shn[4][64];               // node h1 pairs, per wave
    __shared__ float2 sigbuf[4][512];           // sigmoid pairs, per wave

    const int t  = threadIdx.x;
    const int l  = t & 63;
    const int wv = t >> 6;
    const int p  = l & 15;            // pair slot within 16-j tile
    const int g  = l >> 4;            // channel group
    const int c4 = g << 2;
    const int ia = blockIdx.x * 8 + wv * 2;   // even global row (b*512 + i0)
    const int ib = ia + 1;
    const int bb = ia >> 9;
    const int i0 = ia & 511, i1 = i0 + 1;

    const float* xb = x + bb * 1024;  // x[b][j][2]

    // ---- Phase 1a: stage pj (f16) into LDS; thread t covers j = t, t+256 ----
    #pragma unroll
    for (int jj = 0; jj < 2; ++jj) {
        const int j = t + jj * 256;
        const float2 xj = *reinterpret_cast<const float2*>(xb + j * 2);
        f16 v[16];
        #pragma unroll
        for (int c = 0; c < 16; ++c)
            v[c] = (f16)fmaf(xj.x, Wc1[c], xj.y * Wc1[16 + c]);
        const int sw = ((j >> 2) & 3) << 3;
        #pragma unroll
        for (int gg = 0; gg < 4; ++gg) {
            const int addr = j * 32 + ((gg << 3) ^ sw);
            *reinterpret_cast<f16x4*>(pjbuf + addr) =
                (f16x4){v[4*gg], v[4*gg+1], v[4*gg+2], v[4*gg+3]};
        }
    }

    const float2 xia = *reinterpret_cast<const float2*>(xb + i0 * 2);
    const float2 xib = *reinterpret_cast<const float2*>(xb + i1 * 2);

    // ---- Phase 1b: weight fragments (row-independent) + per-row piu ----
    f16x4 w2h, piua, piub;
    f32x4 c1;
    float w3p[4], w3a[4];
    #pragma unroll
    for (int e = 0; e < 4; ++e) {
        const int c = c4 + e;
        w2h[e] = (f16)Wc2[c * 16 + p];       // RTN f16 (single-MFMA path)
        c1[e]  = bc2[c];
        const float w3 = Wc3[c];
        w3p[e] = 0.505f * w3;
        w3a[e] = 0.495f * w3;
        const float wi0 = Wc1[32 + c], wi1 = Wc1[48 + c], bce = bc1[c];
        piua[e] = (f16)fmaf(xia.x, wi0, fmaf(xia.y, wi1, bce));
        piub[e] = (f16)fmaf(xib.x, wi0, fmaf(xib.y, wi1, bce));
    }
    const f16x4 slope4 = {(f16)NEG_SLOPE, (f16)NEG_SLOPE, (f16)NEG_SLOPE, (f16)NEG_SLOPE};

    // ---- Phase 1c: node MLP for both rows (shared Wn2 loads, split chains) ----
    const float h1a = leaky(fmaf(xia.x, Wn1[l], fmaf(xia.y, Wn1[64 + l], bn1[l])));
    const float h1b = leaky(fmaf(xib.x, Wn1[l], fmaf(xib.y, Wn1[64 + l], bn1[l])));
    shn[wv][l] = make_float2(h1a, h1b);
    float na0 = bn2[l], nb0 = 0.f, na1 = 0.f, nb1 = 0.f;
    #pragma unroll 8
    for (int c = 0; c < 64; c += 2) {
        const float w0 = Wn2[c * 64 + l];
        const float w1 = Wn2[(c + 1) * 64 + l];
        const float2 h0 = shn[wv][c];
        const float2 h2 = shn[wv][c + 1];
        na0 = fmaf(h0.x, w0, na0);
        nb0 = fmaf(h0.y, w0, nb0);
        na1 = fmaf(h2.x, w1, na1);
        nb1 = fmaf(h2.y, w1, nb1);
    }
    const float node_a = leaky(na0 + na1) * Wn3[l];
    const float node_b = leaky(nb0 + nb1 + bn2[l]) * Wn3[l];

    // ---- Phase 1d: sigmoid rows for both i's -> LDS (intra-wave use) ----
    float vsa = 0.f, vsb = 0.f;
    const float* Ara = A_param + i0 * 512;
    const float* Arb = Ara + 512;
    #pragma unroll
    for (int s = 0; s < 8; ++s) {
        const int j = s * 64 + l;
        float sa = __fdividef(1.f, 1.f + __expf(-Ara[j]));
        float sb = __fdividef(1.f, 1.f + __expf(-Arb[j]));
        if (j == i0) sa = 0.f;        // sigmoid(0 - 1e5) == 0 in f32
        if (j == i1) sb = 0.f;
        vsa += sa; vsb += sb;
        sigbuf[wv][j] = make_float2(sa, sb);
    }

    __syncthreads();   // pjbuf staging complete (shn/sigbuf are intra-wave)

    // ---- Phase 2: 32 subtiles; depth-2 LDS prefetch; 1-stage result pipe ----
    const int rbase = p * 32 + ((g << 3) ^ (((p >> 2) & 3) << 3));
    float pA0=0.f,pA1=0.f,pA2=0.f,pA3=0.f, qA0=0.f,qA1=0.f,qA2=0.f,qA3=0.f;
    float pB0=0.f,pB1=0.f,pB2=0.f,pB3=0.f, qB0=0.f,qB1=0.f,qB2=0.f,qB3=0.f;

    f16x4  pj0 = *reinterpret_cast<const f16x4*>(pjbuf + rbase);            // tile 0
    float2 sg0 = sigbuf[wv][p];
    f16x4  pj1 = *reinterpret_cast<const f16x4*>(pjbuf + rbase + 512);      // tile 1
    float2 sg1 = sigbuf[wv][16 + p];

    // prologue: issue tile 0's MFMAs; refill pj1 with tile 2
    f16x4 s4a = pj0 + piua;
    f16x4 b1a = __builtin_elementwise_max(s4a, s4a * slope4);
    f16x4 s4b = pj0 + piub;
    f16x4 b1b = __builtin_elementwise_max(s4b, s4b * slope4);
    f32x4 dpa = __builtin_amdgcn_mfma_f32_16x16x16f16(w2h, b1a, c1, 0, 0, 0);
    f32x4 dpb = __builtin_amdgcn_mfma_f32_16x16x16f16(w2h, b1b, c1, 0, 0, 0);
    float spa = sg0.x, spb = sg0.y;                                         // tile 0 sig
    pj0 = pj1; sg0 = sg1;                                                   // -> tile 1
    pj1 = *reinterpret_cast<const f16x4*>(pjbuf + rbase + 2 * 512);         // tile 2
    sg1 = sigbuf[wv][2 * 16 + p];

    #pragma unroll 4
    for (int T = 1; T < 32; ++T) {
        // prefetch tile T+2 (wraps to dummy on last two iters)
        const int Tn = (T + 2) & 31;
        const f16x4  pjn = *reinterpret_cast<const f16x4*>(pjbuf + rbase + Tn * 512);
        const float2 sgn = sigbuf[wv][Tn * 16 + p];

        // issue tile T's MFMAs
        s4a = pj0 + piua;
        b1a = __builtin_elementwise_max(s4a, s4a * slope4);
        s4b = pj0 + piub;
        b1b = __builtin_elementwise_max(s4b, s4b * slope4);
        const f32x4 dca = __builtin_amdgcn_mfma_f32_16x16x16f16(w2h, b1a, c1, 0, 0, 0);
        const f32x4 dcb = __builtin_amdgcn_mfma_f32_16x16x16f16(w2h, b1b, c1, 0, 0, 0);

        // accumulate tile T-1's results (overlaps the MFMAs above)
        pA0 = fmaf(spa, dpa[0], pA0);  qA0 = fmaf(spa, fabsf(dpa[0]), qA0);
        pA1 = fmaf(spa, dpa[1], pA1);  qA1 = fmaf(spa, fabsf(dpa[1]), qA1);
        pA2 = fmaf(spa, dpa[2], pA2);  qA2 = fmaf(spa, fabsf(dpa[2]), qA2);
        pA3 = fmaf(spa, dpa[3], pA3);  qA3 = fmaf(spa, fabsf(dpa[3]), qA3);
        pB0 = fmaf(spb, dpb[0], pB0);  qB0 = fmaf(spb, fabsf(dpb[0]), qB0);
        pB1 = fmaf(spb, dpb[1], pB1);  qB1 = fmaf(spb, fabsf(dpb[1]), qB1);
        pB2 = fmaf(spb, dpb[2], pB2);  qB2 = fmaf(spb, fabsf(dpb[2]), qB2);
        pB3 = fmaf(spb, dpb[3], pB3);  qB3 = fmaf(spb, fabsf(dpb[3]), qB3);

        // rotate: results, sig, and LDS pipeline
        dpa = dca; dpb = dcb;
        spa = sg0.x; spb = sg0.y;     // tile T's sig
        pj0 = pj1; sg0 = sg1;         // -> tile T+1
        pj1 = pjn; sg1 = sgn;         // -> tile T+2
    }

    // epilogue: accumulate tile 31's results
    pA0 = fmaf(spa, dpa[0], pA0);  qA0 = fmaf(spa, fabsf(dpa[0]), qA0);
    pA1 = fmaf(spa, dpa[1], pA1);  qA1 = fmaf(spa, fabsf(dpa[1]), qA1);
    pA2 = fmaf(spa, dpa[2], pA2);  qA2 = fmaf(spa, fabsf(dpa[2]), qA2);
    pA3 = fmaf(spa, dpa[3], pA3);  qA3 = fmaf(spa, fabsf(dpa[3]), qA3);
    pB0 = fmaf(spb, dpb[0], pB0);  qB0 = fmaf(spb, fabsf(dpb[0]), qB0);
    pB1 = fmaf(spb, dpb[1], pB1);  qB1 = fmaf(spb, fabsf(dpb[1]), qB1);
    pB2 = fmaf(spb, dpb[2], pB2);  qB2 = fmaf(spb, fabsf(dpb[2]), qB2);
    pB3 = fmaf(spb, dpb[3], pB3);  qB3 = fmaf(spb, fabsf(dpb[3]), qB3);

    // ---- Epilogue: leaky fold (0.505/0.495 in w3p/w3a), node, butterfly ----
    float ppa = pA0*w3p[0] + qA0*w3a[0] + pA1*w3p[1] + qA1*w3a[1]
              + pA2*w3p[2] + qA2*w3a[2] + pA3*w3p[3] + qA3*w3a[3];
    float ppb = pB0*w3p[0] + qB0*w3a[0] + pB1*w3p[1] + qB1*w3a[1]
              + pB2*w3p[2] + qB2*w3a[2] + pB3*w3p[3] + qB3*w3a[3];

    ppa = fmaf(bc3[0], vsa, ppa) + node_a;
    ppb = fmaf(bc3[0], vsb, ppb) + node_b;

    #pragma unroll
    for (int off = 32; off > 0; off >>= 1) {
        ppa += __shfl_xor(ppa, off, 64);
        ppb += __shfl_xor(ppb, off, 64);
    }

    if (l == 0) {
        out[ia * 2 + 0] = xia.y;               // out0 = x[...,1]
        out[ia * 2 + 1] = ppa + bn3[0];
        out[ib * 2 + 0] = xib.y;
        out[ib * 2 + 1] = ppb + bn3[0];
    }
}

extern "C" void kernel_launch(void* const* d_in, const int* in_sizes, int n_in,
                              void* d_out, int out_size, void* d_ws, size_t ws_size,
                              hipStream_t stream) {
    const float* x       = (const float*)d_in[0];
    const float* Wn1     = (const float*)d_in[1];
    const float* bn1     = (const float*)d_in[2];
    const float* Wn2     = (const float*)d_in[3];
    const float* bn2     = (const float*)d_in[4];
    const float* Wn3     = (const float*)d_in[5];
    const float* bn3     = (const float*)d_in[6];
    const float* Wc1     = (const float*)d_in[7];
    const float* bc1     = (const float*)d_in[8];
    const float* Wc2     = (const float*)d_in[9];
    const float* bc2     = (const float*)d_in[10];
    const float* Wc3     = (const float*)d_in[11];
    const float* bc3     = (const float*)d_in[12];
    const float* A_param = (const float*)d_in[13];
    float* out = (float*)d_out;

    const int BN = 16 * 512;          // 8192 rows; 8 per block (2 per wave)

    fused_pipe2<<<BN / 8, 256, 0, stream>>>(x, Wn1, bn1, Wn2, bn2, Wn3, bn3,
                                            Wc1, bc1, Wc2, bc2, Wc3, bc3,
                                            A_param, out);
}